// Round 6
// baseline (138.396 us; speedup 1.0000x reference)
//
#include <hip/hip_runtime.h>
#include <hip/hip_bf16.h>

// flex_conv via MFMA + register sliding-window column sweep (v6).
//
// Math (unchanged, validated): t[k=ic*4+d][pixel]: t_d = ctr_d*Xs - PX_d
// (d<3), t_3 = Xs; out[o][pixel] = Kmat[o][k] . t[k][pixel] -> 16x16x32 bf16
// MFMA (A[m=p][k], B[k][n=p], D row=c*4+r col=p).
//
// v1-v5 post-mortem: duration pinned 42-52 us across 5 schedules; warm
// iterations show fetch ~2 MB (input cache-resident) yet 46 us at 1500 GB/s
// -> NOT bandwidth-bound, NOT barrier-bound (v5 had no barrier), NOT
// occupancy-capacity-bound (v4's 4x occupancy was neutral).  VALUBusy ~20%
// = waves stalled on vmcnt ~80%: latency-bound, too little independent
// work per wave (v5: 84-load bursts per 2 output rows, full drain at each
// B-pack).
//
// v6: one wave (64 thr) owns a 16-col x 8-row output column.  Vertical
// sliding window in REGISTERS: stage 10 input rows (21 loads each),
// keep a 3-row ring of horizontal partials (rsx, r0..r2 per t; 48 VGPRs,
// compile-time ring indices -> registers), emit one output row (B-pack,
// 4 MFMA, 8 stores) per iteration from ir>=2.  Straight-line unrolled
// dataflow, no barriers: compiler hoists row r+1's loads under row r's
// compute.  Loads/output-row 42 -> 26; A-fragment setup amortized 4x.
// __launch_bounds__(64,4) caps VGPR at 128 -> 16 waves/CU; grid 32x8x16
// = 4096 waves = exactly 16/CU.

#define HH 64
#define WW 512
#define HP 62
#define WP 510
#define IC 16
#define OC 32
#define BS 16
#define NR 8            // output rows per wave

typedef __attribute__((ext_vector_type(8))) short short8;
typedef __attribute__((ext_vector_type(4))) float f32x4;

static __device__ __forceinline__ short f2bf(float f) {
    union { __hip_bfloat16 h; short s; } u;
    u.h = __float2bfloat16(f);
    return u.s;
}

__global__ __launch_bounds__(64, 4) void flex_conv_col(
    const float* __restrict__ x, const float* __restrict__ kern,
    const float* __restrict__ pts, float* __restrict__ out)
{
    const int lane = threadIdx.x;        // 0..63, one wave per block
    const int p = lane & 15;
    const int c = lane >> 4;

    const int j0 = blockIdx.x * 16;
    int i0 = blockIdx.y * NR;
    if (i0 > HP - NR) i0 = HP - NR;      // 54: tail overlap, identical rewrite
    const int b = blockIdx.z;

    const int j = j0 + p;                // output col of this lane
    int jc = j;
    if (jc > WW - 3) jc = WW - 3;        // clamp reads; garbage col never stored

    const float* xb = x   + (size_t)b * IC * HH * WW + (size_t)i0 * WW + jc;
    const float* pb = pts + (size_t)b * 3  * HH * WW + (size_t)i0 * WW + jc;
    float* const ob = out + (size_t)b * OC * HP * WP + j;

    // ---- A fragments: Kmat rows o=p / o=16+p, k-chunks c*8 and 32+c*8 ----
    short8 a0lo, a0hi, a1lo, a1hi;
    {
        const float4* k0v = (const float4*)(kern + (size_t)p * 64 + c * 8);
        const float4* k1v = (const float4*)(kern + (size_t)(16 + p) * 64 + c * 8);
        float4 v0a = k0v[0], v0b = k0v[1], v0c = k0v[8], v0d = k0v[9];
        float4 v1a = k1v[0], v1b = k1v[1], v1c = k1v[8], v1d = k1v[9];
        a0lo[0]=f2bf(v0a.x); a0lo[1]=f2bf(v0a.y); a0lo[2]=f2bf(v0a.z); a0lo[3]=f2bf(v0a.w);
        a0lo[4]=f2bf(v0b.x); a0lo[5]=f2bf(v0b.y); a0lo[6]=f2bf(v0b.z); a0lo[7]=f2bf(v0b.w);
        a0hi[0]=f2bf(v0c.x); a0hi[1]=f2bf(v0c.y); a0hi[2]=f2bf(v0c.z); a0hi[3]=f2bf(v0c.w);
        a0hi[4]=f2bf(v0d.x); a0hi[5]=f2bf(v0d.y); a0hi[6]=f2bf(v0d.z); a0hi[7]=f2bf(v0d.w);
        a1lo[0]=f2bf(v1a.x); a1lo[1]=f2bf(v1a.y); a1lo[2]=f2bf(v1a.z); a1lo[3]=f2bf(v1a.w);
        a1lo[4]=f2bf(v1b.x); a1lo[5]=f2bf(v1b.y); a1lo[6]=f2bf(v1b.z); a1lo[7]=f2bf(v1b.w);
        a1hi[0]=f2bf(v1c.x); a1hi[1]=f2bf(v1c.y); a1hi[2]=f2bf(v1c.z); a1hi[3]=f2bf(v1c.w);
        a1hi[4]=f2bf(v1d.x); a1hi[5]=f2bf(v1d.y); a1hi[6]=f2bf(v1d.z); a1hi[7]=f2bf(v1d.w);
    }

    // ---- 3-row ring of horizontal window partials (compile-time indexed) ----
    float rsx[3][4], r0s[3][4], r1s[3][4], r2s[3][4];
    float cm0[3], cm1[3], cm2[3];

    #pragma unroll
    for (int ir = 0; ir < NR + 2; ++ir) {
        const int sl = ir % 3;
        // pts row ir (3 planes, 3 cols each)
        const float* q0 = pb + (size_t)ir * WW;
        const float* q1 = q0 + (size_t)HH * WW;
        const float* q2 = q1 + (size_t)HH * WW;
        const float pa0 = q0[0], pm0 = q0[1], pz0 = q0[2];
        const float pa1 = q1[0], pm1 = q1[1], pz1 = q1[2];
        const float pa2 = q2[0], pm2 = q2[1], pz2 = q2[2];
        cm0[sl] = pm0; cm1[sl] = pm1; cm2[sl] = pm2;
        // x row ir for this lane's 4 ic-planes -> horizontal partials
        #pragma unroll
        for (int t = 0; t < 4; ++t) {
            const int ic = (t >> 1) * 8 + 2 * c + (t & 1);
            const float* lx = xb + ((size_t)ic * HH + ir) * WW;
            const float x0 = lx[0], x1 = lx[1], x2 = lx[2];
            rsx[sl][t] = x0 + x1 + x2;
            float a = pa0 * x0; a = fmaf(pm0, x1, a); a = fmaf(pz0, x2, a); r0s[sl][t] = a;
            float d = pa1 * x0; d = fmaf(pm1, x1, d); d = fmaf(pz1, x2, d); r1s[sl][t] = d;
            float e = pa2 * x0; e = fmaf(pm2, x1, e); e = fmaf(pz2, x2, e); r2s[sl][t] = e;
        }
        // emit output row io = i0 + ir - 2 (window rows ir-2..ir, ctr row ir-1)
        if (ir >= 2) {
            const int io = i0 + ir - 2;
            const int mid = (ir - 1) % 3;
            const float cc0 = cm0[mid], cc1 = cm1[mid], cc2 = cm2[mid];
            short8 blo, bhi;
            #pragma unroll
            for (int t = 0; t < 4; ++t) {
                const float XS = rsx[0][t] + rsx[1][t] + rsx[2][t];
                const float P0 = r0s[0][t] + r0s[1][t] + r0s[2][t];
                const float P1 = r1s[0][t] + r1s[1][t] + r1s[2][t];
                const float P2 = r2s[0][t] + r2s[1][t] + r2s[2][t];
                const short t0 = f2bf(fmaf(cc0, XS, -P0));
                const short t1 = f2bf(fmaf(cc1, XS, -P1));
                const short t2 = f2bf(fmaf(cc2, XS, -P2));
                const short t3 = f2bf(XS);
                const int s = (t & 1) * 4;
                if (t < 2) { blo[s+0]=t0; blo[s+1]=t1; blo[s+2]=t2; blo[s+3]=t3; }
                else       { bhi[s+0]=t0; bhi[s+1]=t1; bhi[s+2]=t2; bhi[s+3]=t3; }
            }
            f32x4 acc0 = {0.f,0.f,0.f,0.f}, acc1 = {0.f,0.f,0.f,0.f};
            acc0 = __builtin_amdgcn_mfma_f32_16x16x32_bf16(a0lo, blo, acc0, 0, 0, 0);
            acc0 = __builtin_amdgcn_mfma_f32_16x16x32_bf16(a0hi, bhi, acc0, 0, 0, 0);
            acc1 = __builtin_amdgcn_mfma_f32_16x16x32_bf16(a1lo, blo, acc1, 0, 0, 0);
            acc1 = __builtin_amdgcn_mfma_f32_16x16x32_bf16(a1hi, bhi, acc1, 0, 0, 0);
            if (j < WP) {
                float* op = ob + (size_t)io * WP;
                #pragma unroll
                for (int r = 0; r < 4; ++r) {
                    const int o = c * 4 + r;
                    op[(size_t)o * HP * WP]        = acc0[r];
                    op[(size_t)(o + 16) * HP * WP] = acc1[r];
                }
            }
        }
    }
}

extern "C" void kernel_launch(void* const* d_in, const int* in_sizes, int n_in,
                              void* d_out, int out_size, void* d_ws, size_t ws_size,
                              hipStream_t stream)
{
    const float* x    = (const float*)d_in[0];
    const float* kern = (const float*)d_in[1];
    const float* pts  = (const float*)d_in[2];
    float* out = (float*)d_out;

    dim3 block(64, 1, 1);
    dim3 grid(WW / 16, (HP + NR - 1) / NR, BS);   // 32 x 8 x 16 = 4096 waves
    flex_conv_col<<<grid, block, 0, stream>>>(x, kern, pts, out);
}

// Round 7
// 113.583 us; speedup vs baseline: 1.2185x; 1.2185x over previous
//
#include <hip/hip_runtime.h>
#include <hip/hip_bf16.h>

// flex_conv via MFMA + async LDS staging + COALESCED LDS-transposed epilogue (v7).
//
// Math (unchanged, validated): t[k=ic*4+d][pixel]: t_d = ctr_d*Xs - PX_d
// (d<3), t_3 = Xs; out[o][pixel] = Kmat[o][k] . t[k][pixel] -> 16x16x32 bf16
// MFMA (A[m=p][k], B[k][n=p], D row=c*4+r col=p).
//
// v1-v6 post-mortem: dur ~= hbm_bytes / ~2.4 TB/s across ALL versions (38%
// of streaming ceiling).  Eliminated: barriers (v5), occupancy (v4), LDS
// staging (v5), VALU work (v6).  The untouched component: the epilogue's 8
// scalar scatter-stores/thread/row -- each wave-instr writes 4x64B half-line
// segments to 4 planes (2x L2 write-request amplification, partial lines).
// v6 corroborates: when 1-wave blocks lost half-line merging, WRITE_SIZE
// rose 69->99 MB and duration scaled with it.
//
// v7 = v4 staging/compute verbatim + new epilogue: park accs -> barrier
// (staging LDS dead) -> scatter accs to LDS out-tile [32][RB][66] (pad 66:
// <=2-way write conflicts = free; rows 8B-aligned) -> barrier -> stream as
// float2: each wave-instr writes 512 B contiguous same-plane data (full
// 128 B lines).  WP=510 even => float2 never straddles a row end; only the
// last tile's cols 510/511 pair is skipped (garbage, never valid).

#define HH 64
#define WW 512
#define HP 62
#define WP 510
#define IC 16
#define OC 32
#define BS 16
#define RB 2            // output rows per block
#define TR (RB + 2)     // staged input rows = 4
#define TC 64           // output cols per block
#define LC 68           // LDS row length in floats (need 66; 68 = 17 float4)
#define NPL 19          // planes staged: 16 x + 3 pts
#define CPR 17          // float4 chunks per row (17*4 = 68)
#define NROWS (NPL * TR)        // 76
#define NCHUNK (NROWS * CPR)    // 1292
#define OLC 66                  // out-tile LDS row length (64 + 2 pad, even)
#define OSTR (RB * OLC)         // per-o stride = 132

typedef __attribute__((ext_vector_type(8))) short short8;
typedef __attribute__((ext_vector_type(4))) float f32x4;

static __device__ __forceinline__ short f2bf(float f) {
    union { __hip_bfloat16 h; short s; } u;
    u.h = __float2bfloat16(f);
    return u.s;
}

__global__ __launch_bounds__(256) void flex_conv_v7(
    const float* __restrict__ x, const float* __restrict__ kern,
    const float* __restrict__ pts, float* __restrict__ out)
{
    __shared__ float lds[NPL * TR * LC];   // 5168 floats = 20672 B
    // out-tile reuse after compute: OC*OSTR = 4224 floats = 16896 B  (fits)

    const int tid = threadIdx.x;
    const int j0 = blockIdx.x * TC;
    const int i0 = blockIdx.y * RB;        // 0..60; rows i0..i0+3 <= 63, in bounds
    const int b = blockIdx.z;

    const float* xb = x + (size_t)b * IC * HH * WW;
    const float* pb = pts + (size_t)b * 3 * HH * WW;

    // ---- async cooperative staging: 1292 16B chunks over 256 threads ----
    #pragma unroll
    for (int rnd = 0; rnd < 6; ++rnd) {
        const int cid = tid + rnd * 256;
        if (cid < NCHUNK) {
            const int row = cid / CPR;           // 0..75 = plane*TR + rr
            const int chunk = cid - row * CPR;   // 0..16
            const int plane = row / TR;          // 0..18
            const int rr = row - plane * TR;     // 0..3
            const float* base = (plane < IC)
                ? (xb + (size_t)plane * HH * WW)
                : (pb + (size_t)(plane - IC) * HH * WW);
            int gcol = j0 + chunk * 4;
            if (gcol > WW - 4) gcol = WW - 4;    // clamp (garbage lands in unused cells)
            const float* src = base + (size_t)(i0 + rr) * WW + gcol;
            __builtin_amdgcn_global_load_lds(
                (const __attribute__((address_space(1))) void*)src,
                (__attribute__((address_space(3))) void*)(&lds[row * LC + chunk * 4]),
                16, 0, 0);
        }
    }

    // ---- A fragments: loaded while the DMA above is in flight ----
    const int lane = tid & 63;
    const int wave = tid >> 6;
    const int p = lane & 15;
    const int c = lane >> 4;
    const int tc = wave * 16 + p;        // tile col of this lane's pixel

    short8 a0lo, a0hi, a1lo, a1hi;
    {
        const float4* k0v = (const float4*)(kern + (size_t)p * 64 + c * 8);
        const float4* k1v = (const float4*)(kern + (size_t)(16 + p) * 64 + c * 8);
        float4 v0a = k0v[0], v0b = k0v[1], v0c = k0v[8], v0d = k0v[9];
        float4 v1a = k1v[0], v1b = k1v[1], v1c = k1v[8], v1d = k1v[9];
        a0lo[0]=f2bf(v0a.x); a0lo[1]=f2bf(v0a.y); a0lo[2]=f2bf(v0a.z); a0lo[3]=f2bf(v0a.w);
        a0lo[4]=f2bf(v0b.x); a0lo[5]=f2bf(v0b.y); a0lo[6]=f2bf(v0b.z); a0lo[7]=f2bf(v0b.w);
        a0hi[0]=f2bf(v0c.x); a0hi[1]=f2bf(v0c.y); a0hi[2]=f2bf(v0c.z); a0hi[3]=f2bf(v0c.w);
        a0hi[4]=f2bf(v0d.x); a0hi[5]=f2bf(v0d.y); a0hi[6]=f2bf(v0d.z); a0hi[7]=f2bf(v0d.w);
        a1lo[0]=f2bf(v1a.x); a1lo[1]=f2bf(v1a.y); a1lo[2]=f2bf(v1a.z); a1lo[3]=f2bf(v1a.w);
        a1lo[4]=f2bf(v1b.x); a1lo[5]=f2bf(v1b.y); a1lo[6]=f2bf(v1b.z); a1lo[7]=f2bf(v1b.w);
        a1hi[0]=f2bf(v1c.x); a1hi[1]=f2bf(v1c.y); a1hi[2]=f2bf(v1c.z); a1hi[3]=f2bf(v1c.w);
        a1hi[4]=f2bf(v1d.x); a1hi[5]=f2bf(v1d.y); a1hi[6]=f2bf(v1d.z); a1hi[7]=f2bf(v1d.w);
    }

    __syncthreads();   // drains staging DMA (vmcnt(0)) + barrier

    // ---- window partials from LDS ----
    float xs[4][RB], px0[4][RB], px1[4][RB], px2[4][RB];
    #pragma unroll
    for (int t = 0; t < 4; ++t)
        #pragma unroll
        for (int q = 0; q < RB; ++q) { xs[t][q]=0.f; px0[t][q]=0.f; px1[t][q]=0.f; px2[t][q]=0.f; }
    float c0[RB], c1[RB], c2[RB];

    #pragma unroll
    for (int rr = 0; rr < TR; ++rr) {
        const float* lp0 = &lds[(IC * TR + rr) * LC + tc];        // pts plane 0
        const float* lp1 = &lds[((IC + 1) * TR + rr) * LC + tc];
        const float* lp2 = &lds[((IC + 2) * TR + rr) * LC + tc];
        const float pa0 = lp0[0], pm0 = lp0[1], pz0 = lp0[2];
        const float pa1 = lp1[0], pm1 = lp1[1], pz1 = lp1[2];
        const float pa2 = lp2[0], pm2 = lp2[1], pz2 = lp2[2];
        if (rr >= 1 && rr <= RB) { c0[rr-1] = pm0; c1[rr-1] = pm1; c2[rr-1] = pm2; }
        #pragma unroll
        for (int t = 0; t < 4; ++t) {
            const int ic = (t >> 1) * 8 + 2 * c + (t & 1);
            const float* lx = &lds[(ic * TR + rr) * LC + tc];
            const float x0 = lx[0], x1 = lx[1], x2 = lx[2];
            const float rsx = x0 + x1 + x2;
            float r0 = pa0 * x0; r0 = fmaf(pm0, x1, r0); r0 = fmaf(pz0, x2, r0);
            float r1 = pa1 * x0; r1 = fmaf(pm1, x1, r1); r1 = fmaf(pz1, x2, r1);
            float r2 = pa2 * x0; r2 = fmaf(pm2, x1, r2); r2 = fmaf(pz2, x2, r2);
            #pragma unroll
            for (int q = 0; q < RB; ++q) {
                if (rr >= q && rr <= q + 2) {
                    xs[t][q] += rsx; px0[t][q] += r0; px1[t][q] += r1; px2[t][q] += r2;
                }
            }
        }
    }

    // ---- B fragments -> MFMA; park accumulators ----
    f32x4 sa0[RB], sa1[RB];
    #pragma unroll
    for (int q = 0; q < RB; ++q) {
        short8 blo, bhi;
        #pragma unroll
        for (int t = 0; t < 4; ++t) {
            const short t0 = f2bf(fmaf(c0[q], xs[t][q], -px0[t][q]));
            const short t1 = f2bf(fmaf(c1[q], xs[t][q], -px1[t][q]));
            const short t2 = f2bf(fmaf(c2[q], xs[t][q], -px2[t][q]));
            const short t3 = f2bf(xs[t][q]);
            const int s = (t & 1) * 4;
            if (t < 2) { blo[s+0]=t0; blo[s+1]=t1; blo[s+2]=t2; blo[s+3]=t3; }
            else       { bhi[s+0]=t0; bhi[s+1]=t1; bhi[s+2]=t2; bhi[s+3]=t3; }
        }
        f32x4 acc0 = {0.f,0.f,0.f,0.f}, acc1 = {0.f,0.f,0.f,0.f};
        acc0 = __builtin_amdgcn_mfma_f32_16x16x32_bf16(a0lo, blo, acc0, 0, 0, 0);
        acc0 = __builtin_amdgcn_mfma_f32_16x16x32_bf16(a0hi, bhi, acc0, 0, 0, 0);
        acc1 = __builtin_amdgcn_mfma_f32_16x16x32_bf16(a1lo, blo, acc1, 0, 0, 0);
        acc1 = __builtin_amdgcn_mfma_f32_16x16x32_bf16(a1hi, bhi, acc1, 0, 0, 0);
        sa0[q] = acc0; sa1[q] = acc1;
    }

    // ---- epilogue: transpose through LDS, then full-line float2 stores ----
    __syncthreads();   // all staging-LDS reads complete; safe to reuse
    #pragma unroll
    for (int q = 0; q < RB; ++q)
        #pragma unroll
        for (int r = 0; r < 4; ++r) {
            lds[(c * 4 + r) * OSTR + q * OLC + tc]        = sa0[q][r];
            lds[(c * 4 + r + 16) * OSTR + q * OLC + tc]   = sa1[q][r];
        }
    __syncthreads();

    // 2048 float2 elements (OC*RB rows x 32 f2/row) over 256 threads:
    // consecutive lanes take consecutive f2 within one plane-row -> each
    // wave-instr stores 512 B of contiguous same-plane data (full lines).
    float* const outb = out + (size_t)b * OC * HP * WP;
    #pragma unroll
    for (int k = 0; k < 8; ++k) {
        const int fid = tid + k * 256;     // 0..2047
        const int f2c = fid & 31;          // float2 col within 64-col tile
        const int rowid = fid >> 5;        // 0..63 = o*RB + q
        const int o = rowid >> 1;
        const int q = rowid & 1;
        const int gc = j0 + 2 * f2c;       // even; gc+1 <= 509 when gc < WP
        if (gc < WP) {
            const float2 v = *(const float2*)(&lds[o * OSTR + q * OLC + 2 * f2c]);
            *(float2*)(outb + (size_t)o * HP * WP + (size_t)(i0 + q) * WP + gc) = v;
        }
    }
}

extern "C" void kernel_launch(void* const* d_in, const int* in_sizes, int n_in,
                              void* d_out, int out_size, void* d_ws, size_t ws_size,
                              hipStream_t stream)
{
    const float* x    = (const float*)d_in[0];
    const float* kern = (const float*)d_in[1];
    const float* pts  = (const float*)d_in[2];
    float* out = (float*)d_out;

    dim3 block(256, 1, 1);
    dim3 grid(WW / TC, HP / RB, BS);   // 8 x 31 x 16 = 3968 blocks
    flex_conv_v7<<<grid, block, 0, stream>>>(x, kern, pts, out);
}